// Round 1
// baseline (593.192 us; speedup 1.0000x reference)
//
#include <hip/hip_runtime.h>
#include <math.h>

#define NN 4096
#define EE 8192
#define HH 128
#define GG 8
#define UCOLS 4224  // 33*128: k=0..31 -> W2 slices, k=32 -> b2 slice

// ---------------------------------------------------------------------------
// Generic fp32 tiled GEMM: C[M,Ncols] = act(A[M,K] @ B + bias)
// B[h, j] = Bbase[(j>>7)*sjk + (j&127) + h*sh]   (sjk=128 => plain row-major)
// Requires: M % 64 == 0, Ncols % 64 == 0, K % 16 == 0. grid=(Ncols/64, M/64).
// ---------------------------------------------------------------------------
__global__ __launch_bounds__(256) void gemm_k(
    const float* __restrict__ A, int K,
    const float* __restrict__ B, long sjk, int sh,
    const float* __restrict__ bias,
    float* __restrict__ C, int ldc, int relu)
{
    __shared__ float As[16][64];   // [k][m] transposed for contiguous m-frag
    __shared__ float Bs[16][64];   // [k][j]
    const int tid = threadIdx.x;
    const int tx = tid & 15, ty = tid >> 4;
    const int j0 = blockIdx.x * 64;
    const int m0 = blockIdx.y * 64;
    const float* Bt = B + (long)(j0 >> 7) * sjk + (j0 & 127);

    const int arow = tid >> 2, acol = (tid & 3) << 2;
    const int bk = tid >> 4, bj = (tid & 15) << 2;

    float c[4][4] = {};
    for (int k0 = 0; k0 < K; k0 += 16) {
        __syncthreads();
        float4 av = *(const float4*)&A[(size_t)(m0 + arow) * K + k0 + acol];
        As[acol + 0][arow] = av.x;
        As[acol + 1][arow] = av.y;
        As[acol + 2][arow] = av.z;
        As[acol + 3][arow] = av.w;
        float4 bv = *(const float4*)&Bt[(size_t)(k0 + bk) * sh + bj];
        *(float4*)&Bs[bk][bj] = bv;
        __syncthreads();
#pragma unroll
        for (int kk = 0; kk < 16; ++kk) {
            const float4 a = *(const float4*)&As[kk][ty << 2];
            const float4 b = *(const float4*)&Bs[kk][tx << 2];
            c[0][0] += a.x * b.x; c[0][1] += a.x * b.y; c[0][2] += a.x * b.z; c[0][3] += a.x * b.w;
            c[1][0] += a.y * b.x; c[1][1] += a.y * b.y; c[1][2] += a.y * b.z; c[1][3] += a.y * b.w;
            c[2][0] += a.z * b.x; c[2][1] += a.z * b.y; c[2][2] += a.z * b.z; c[2][3] += a.z * b.w;
            c[3][0] += a.w * b.x; c[3][1] += a.w * b.y; c[3][2] += a.w * b.z; c[3][3] += a.w * b.w;
        }
    }
    float b0 = 0.f, b1 = 0.f, b2 = 0.f, b3 = 0.f;
    if (bias) {
        const float4 bv = *(const float4*)&bias[j0 + (tx << 2)];
        b0 = bv.x; b1 = bv.y; b2 = bv.z; b3 = bv.w;
    }
#pragma unroll
    for (int i = 0; i < 4; ++i) {
        float4 o;
        o.x = c[i][0] + b0; o.y = c[i][1] + b1; o.z = c[i][2] + b2; o.w = c[i][3] + b3;
        if (relu) {
            o.x = fmaxf(o.x, 0.f); o.y = fmaxf(o.y, 0.f);
            o.z = fmaxf(o.z, 0.f); o.w = fmaxf(o.w, 0.f);
        }
        *(float4*)&C[(size_t)(m0 + (ty << 2) + i) * ldc + j0 + (tx << 2)] = o;
    }
}

// ---------------------------------------------------------------------------
// Per-edge message + scatter: msg[e,o] = U[r,32,o] + sum_k eh[e,k]*U[r,k,o]
// eh[e,k] = relu(edge_attr[e]*w1[k] + b1[k]); atomicAdd into agg[col[e],o].
// 2 edges per 256-thread block.
// ---------------------------------------------------------------------------
__global__ __launch_bounds__(256) void edge_msg_k(
    const int* __restrict__ ei, const float* __restrict__ eattr,
    const float* __restrict__ w1, const float* __restrict__ b1,
    const float* __restrict__ U, float* __restrict__ agg)
{
    __shared__ float eh[2][32];
    const int half = threadIdx.x >> 7;
    const int o = threadIdx.x & 127;
    const int e = blockIdx.x * 2 + half;
    if (o < 32) {
        float v = eattr[e] * w1[o] + b1[o];
        eh[half][o] = v > 0.f ? v : 0.f;
    }
    __syncthreads();
    const int r = ei[e];
    const int c = ei[EE + e];
    const float* Ur = U + (size_t)r * UCOLS;
    float acc = Ur[4096 + o];
#pragma unroll
    for (int k = 0; k < 32; ++k) acc += eh[half][k] * Ur[k * 128 + o];
    atomicAdd(&agg[(size_t)c * 128 + o], acc);
}

__global__ void deg_k(const int* __restrict__ ei, float* __restrict__ deg) {
    int e = blockIdx.x * 256 + threadIdx.x;
    if (e < EE) atomicAdd(&deg[ei[EE + e]], 1.0f);
}

__global__ void invdeg_k(float* __restrict__ deg) {
    int n = blockIdx.x * 256 + threadIdx.x;
    if (n < NN) { float d = deg[n]; deg[n] = d > 0.f ? 1.0f / d : 0.0f; }
}

// m = relu(xr + agg * inv_deg[n])    (conv_b already added as GEMM bias)
__global__ void mcomb_k(const float* __restrict__ xr, const float* __restrict__ agg,
                        const float* __restrict__ inv, float* __restrict__ m) {
    int idx = blockIdx.x * 256 + threadIdx.x;
    float v = xr[idx] + agg[idx] * inv[idx >> 7];
    m[idx] = v > 0.f ? v : 0.f;
}

// GRU gate combine, in-place h update
__global__ void gate_k(const float* __restrict__ G1, const float* __restrict__ G2,
                       float* __restrict__ xh) {
    int idx = blockIdx.x * 256 + threadIdx.x;
    int n = idx >> 7, o = idx & 127;
    size_t b = (size_t)n * 384;
    float ir = G1[b + o], iz = G1[b + 128 + o], in_ = G1[b + 256 + o];
    float hr = G2[b + o], hz = G2[b + 128 + o], hn = G2[b + 256 + o];
    float r = 1.f / (1.f + expf(-(ir + hr)));
    float z = 1.f / (1.f + expf(-(iz + hz)));
    float nv = tanhf(in_ + r * hn);
    float hv = xh[idx];
    xh[idx] = (1.f - z) * nv + z * hv;
}

__global__ void transp_k(const float* __restrict__ wih, const float* __restrict__ whh,
                         float* __restrict__ wihT, float* __restrict__ whhT) {
    int idx = blockIdx.x * 256 + threadIdx.x;  // 384*128
    int j = idx >> 7, h = idx & 127;
    wihT[h * 384 + j] = wih[idx];
    whhT[h * 384 + j] = whh[idx];
}

__global__ void cnt_k(const int* __restrict__ batch, float* __restrict__ cnt) {
    __shared__ float loc[GG];
    if (threadIdx.x < GG) loc[threadIdx.x] = 0.f;
    __syncthreads();
    for (int n = threadIdx.x; n < NN; n += 256) atomicAdd(&loc[batch[n]], 1.0f);
    __syncthreads();
    if (threadIdx.x < GG) cnt[threadIdx.x] = loc[threadIdx.x];
}

// batch is sorted: run-length accumulate, flush on graph change. 128 nodes/block.
__global__ __launch_bounds__(128) void pool_k(const int* __restrict__ batch,
                                              const float* __restrict__ xh,
                                              float* __restrict__ pooled) {
    const int o = threadIdx.x;
    const int n0 = blockIdx.x * 128;
    float acc = 0.f;
    int curg = batch[n0];
    for (int i = 0; i < 128; ++i) {
        int n = n0 + i;
        int g = batch[n];
        if (g != curg) {
            atomicAdd(&pooled[curg * 128 + o], acc);
            acc = 0.f; curg = g;
        }
        acc += xh[(size_t)n * 128 + o];
    }
    atomicAdd(&pooled[curg * 128 + o], acc);
}

__global__ __launch_bounds__(128) void final_k(
    const float* __restrict__ pooled, const float* __restrict__ cnt,
    const float* __restrict__ l1w, const float* __restrict__ l1b,
    const float* __restrict__ l2w, const float* __restrict__ l2b,
    float* __restrict__ out)
{
    __shared__ float gv[128];
    __shared__ float sy[64];
    const int t = threadIdx.x;
    for (int g = 0; g < GG; ++g) {
        float c = cnt[g]; c = c > 1.f ? c : 1.f;
        gv[t] = pooled[g * 128 + t] / c;
        __syncthreads();
        if (t < 64) {
            float y = l1b[t];
            for (int h = 0; h < 128; ++h) y += gv[h] * l1w[h * 64 + t];
            y = y > 0.f ? y : 0.f;
            sy[t] = y * l2w[t];
        }
        __syncthreads();
        if (t == 0) {
            float s = l2b[0];
            for (int j = 0; j < 64; ++j) s += sy[j];
            out[g] = s;
        }
        __syncthreads();
    }
}

extern "C" void kernel_launch(void* const* d_in, const int* in_sizes, int n_in,
                              void* d_out, int out_size, void* d_ws, size_t ws_size,
                              hipStream_t stream) {
    const float* x      = (const float*)d_in[0];
    const int*   ei     = (const int*)d_in[1];
    const float* eattr  = (const float*)d_in[2];
    const int*   batch  = (const int*)d_in[3];
    const float* lin0_w = (const float*)d_in[4];
    const float* lin0_b = (const float*)d_in[5];
    const float* nn_w1  = (const float*)d_in[6];
    const float* nn_b1  = (const float*)d_in[7];
    const float* nn_w2  = (const float*)d_in[8];
    const float* nn_b2  = (const float*)d_in[9];
    const float* root_w = (const float*)d_in[10];
    const float* conv_b = (const float*)d_in[11];
    const float* gwih   = (const float*)d_in[12];
    const float* gwhh   = (const float*)d_in[13];
    const float* gbih   = (const float*)d_in[14];
    const float* gbhh   = (const float*)d_in[15];
    const float* l1w    = (const float*)d_in[16];
    const float* l1b    = (const float*)d_in[17];
    const float* l2w    = (const float*)d_in[18];
    const float* l2b    = (const float*)d_in[19];
    float* out = (float*)d_out;
    float* ws  = (float*)d_ws;

    // workspace layout (float offsets)
    float* xh     = ws;                       // [4096,128]  x == h throughout
    float* U      = ws + 524288;              // [4096,4224]
    float* agg    = ws + 17825792;            // [4096,128]
    float* xr     = ws + 18350080;            // [4096,128]
    float* mb     = ws + 18874368;            // [4096,128]
    float* g1     = ws + 19398656;            // [4096,384]
    float* g2     = ws + 20971520;            // [4096,384]
    float* deg    = ws + 22544384;            // [4096] -> becomes inv_deg
    float* wihT   = ws + 22548480;            // [128,384]
    float* whhT   = ws + 22597632;            // [128,384]
    float* pooled = ws + 22646784;            // [8,128]
    float* cnt    = ws + 22647808;            // [8]

    transp_k<<<192, 256, 0, stream>>>(gwih, gwhh, wihT, whhT);

    // x0 = relu(x @ lin0_w + lin0_b)
    gemm_k<<<dim3(2, 64), 256, 0, stream>>>(x, 64, lin0_w, 128, 128, lin0_b, xh, 128, 1);

    hipMemsetAsync(deg, 0, NN * sizeof(float), stream);
    deg_k<<<EE / 256, 256, 0, stream>>>(ei, deg);
    invdeg_k<<<NN / 256, 256, 0, stream>>>(deg);

    for (int t = 0; t < 3; ++t) {
        // U[:, k<32] = x @ W2[t]   (B[h, k*128+o] = W2[k*16384 + h*128 + o])
        gemm_k<<<dim3(64, 64), 256, 0, stream>>>(
            xh, 128, nn_w2 + (size_t)t * 524288, 16384, 128, nullptr, U, UCOLS, 0);
        // U[:, k=32] = x @ reshape(b2,[128,128])
        gemm_k<<<dim3(2, 64), 256, 0, stream>>>(
            xh, 128, nn_b2 + t * 16384, 128, 128, nullptr, U + 4096, UCOLS, 0);

        hipMemsetAsync(agg, 0, (size_t)NN * HH * sizeof(float), stream);
        edge_msg_k<<<EE / 2, 256, 0, stream>>>(ei, eattr, nn_w1 + t * 32, nn_b1 + t * 32, U, agg);

        // xr = x @ root_w[t] + conv_b[t]
        gemm_k<<<dim3(2, 64), 256, 0, stream>>>(
            xh, 128, root_w + t * 16384, 128, 128, conv_b + t * 128, xr, 128, 0);
        mcomb_k<<<(NN * HH) / 256, 256, 0, stream>>>(xr, agg, deg, mb);

        // GRU: g1 = m @ wih^T + bih ; g2 = h @ whh^T + bhh ; combine in place
        gemm_k<<<dim3(6, 64), 256, 0, stream>>>(mb, 128, wihT, 128, 384, gbih, g1, 384, 0);
        gemm_k<<<dim3(6, 64), 256, 0, stream>>>(xh, 128, whhT, 128, 384, gbhh, g2, 384, 0);
        gate_k<<<(NN * HH) / 256, 256, 0, stream>>>(g1, g2, xh);
    }

    hipMemsetAsync(pooled, 0, GG * HH * sizeof(float), stream);
    cnt_k<<<1, 256, 0, stream>>>(batch, cnt);
    pool_k<<<NN / 128, 128, 0, stream>>>(batch, xh, pooled);
    final_k<<<1, 128, 0, stream>>>(pooled, cnt, l1w, l1b, l2w, l2b, out);
}

// Round 2
// 413.016 us; speedup vs baseline: 1.4362x; 1.4362x over previous
//
#include <hip/hip_runtime.h>
#include <math.h>

#define NN 4096
#define EE 8192
#define HH 128
#define GG 8
#define ULD 4352          // big GEMM cols: 4096 (W2) + 128 (b2) + 128 (root)
#define KSP 384           // split-bf16 K: [Ah|Ah|Al] x [Bh|Bl|Bh]

typedef __attribute__((ext_vector_type(8))) short short8;
typedef __attribute__((ext_vector_type(4))) float floatx4;

__device__ __forceinline__ ushort rne_bf16(float v) {
    unsigned u = __float_as_uint(v);
    return (ushort)((u + 0x7fffu + ((u >> 16) & 1u)) >> 16);
}
__device__ __forceinline__ float bf16_f(ushort h) {
    return __uint_as_float(((unsigned)h) << 16);
}
// write [hi, hi, lo] at cols c, 128+c, 256+c of a 384-wide row
__device__ __forceinline__ void split3A(float v, ushort* base, int c) {
    ushort hi = rne_bf16(v);
    ushort lo = rne_bf16(v - bf16_f(hi));
    base[c] = hi; base[128 + c] = hi; base[256 + c] = lo;
}
// B-side rows: [hi, lo, hi]
__device__ __forceinline__ void split3B(float v, ushort* base, int h) {
    ushort hi = rne_bf16(v);
    ushort lo = rne_bf16(v - bf16_f(hi));
    base[h] = hi; base[128 + h] = lo; base[256 + h] = hi;
}

__device__ __forceinline__ void ldst16(const ushort* g, void* l) {
    __builtin_amdgcn_global_load_lds(
        (const __attribute__((address_space(1))) unsigned int*)g,
        (__attribute__((address_space(3))) unsigned int*)l, 16, 0, 0);
}

// ---------------------------------------------------------------------------
// Split-bf16 MFMA GEMM: C[M,ldc] = A'[M,384] @ B'T[N,384]^T (+bias[col])
// 128x128 tile/block, 256 threads (4 waves, 2x2 of 64x64), BK=32, K=384.
// blockIdx.z selects operand set (for fusing the two GRU GEMMs).
// ---------------------------------------------------------------------------
__global__ __launch_bounds__(256) void mgemm_k(
    const ushort* __restrict__ A0, const ushort* __restrict__ B0,
    const float* __restrict__ bias0, float* __restrict__ C0, int ldc0,
    const ushort* __restrict__ A1, const ushort* __restrict__ B1,
    const float* __restrict__ bias1, float* __restrict__ C1, int ldc1)
{
    const ushort* A = A0; const ushort* B = B0; const float* bias = bias0;
    float* C = C0; int ldc = ldc0;
    if (blockIdx.z == 1) { A = A1; B = B1; bias = bias1; C = C1; ldc = ldc1; }

    __shared__ __align__(16) ushort As[128 * 32];  // [row][k]
    __shared__ __align__(16) ushort Bs[128 * 32];  // [col][k]
    const int tid = threadIdx.x;
    const int lane = tid & 63, wave = tid >> 6;
    const int m0 = blockIdx.y * 128, n0 = blockIdx.x * 128;
    const int wr = (wave >> 1) * 64, wc = (wave & 1) * 64;
    const int fm = lane & 15, fq = lane >> 4;

    // staging: chunk c -> LDS byte c*16 == row(c>>2), k-part (c&3)*8
    const int srow = tid >> 2, soff = (tid & 3) << 3;
    const ushort* gA0 = A + (size_t)(m0 + srow) * KSP + soff;
    const ushort* gA1 = gA0 + (size_t)64 * KSP;
    const ushort* gB0 = B + (size_t)(n0 + srow) * KSP + soff;
    const ushort* gB1 = gB0 + (size_t)64 * KSP;
    char* lA0 = (char*)As + tid * 16;  char* lA1 = (char*)As + (tid + 256) * 16;
    char* lB0 = (char*)Bs + tid * 16;  char* lB1 = (char*)Bs + (tid + 256) * 16;

    floatx4 acc[4][4] = {};
    for (int k0 = 0; k0 < KSP; k0 += 32) {
        __syncthreads();
        ldst16(gA0 + k0, lA0); ldst16(gA1 + k0, lA1);
        ldst16(gB0 + k0, lB0); ldst16(gB1 + k0, lB1);
        __syncthreads();   // compiler drains vmcnt before barrier
        short8 af[4], bf[4];
#pragma unroll
        for (int i = 0; i < 4; ++i)
            af[i] = *(const short8*)&As[(wr + i * 16 + fm) * 32 + fq * 8];
#pragma unroll
        for (int j = 0; j < 4; ++j)
            bf[j] = *(const short8*)&Bs[(wc + j * 16 + fm) * 32 + fq * 8];
#pragma unroll
        for (int i = 0; i < 4; ++i)
#pragma unroll
            for (int j = 0; j < 4; ++j)
                acc[i][j] = __builtin_amdgcn_mfma_f32_16x16x32_bf16(
                    af[i], bf[j], acc[i][j], 0, 0, 0);
    }
    // C/D layout: col = lane&15, row = (lane>>4)*4 + reg  [m89-verified]
    const int er = fq * 4, ec = fm;
#pragma unroll
    for (int i = 0; i < 4; ++i) {
        const int gr = m0 + wr + i * 16 + er;
#pragma unroll
        for (int j = 0; j < 4; ++j) {
            const int gc = n0 + wc + j * 16 + ec;
            const float bv = bias ? bias[gc] : 0.0f;
#pragma unroll
            for (int r = 0; r < 4; ++r)
                C[(size_t)(gr + r) * ldc + gc] = acc[i][j][r] + bv;
        }
    }
}

// ---------------------------------------------------------------------------
// fp32 tiled GEMM (kept for lin0 only: [4096,64]@[64,128])
// ---------------------------------------------------------------------------
__global__ __launch_bounds__(256) void gemm_k(
    const float* __restrict__ A, int K,
    const float* __restrict__ B, int sh,
    const float* __restrict__ bias,
    float* __restrict__ C, int ldc, int relu)
{
    __shared__ float As[16][64];
    __shared__ float Bs[16][64];
    const int tid = threadIdx.x;
    const int tx = tid & 15, ty = tid >> 4;
    const int j0 = blockIdx.x * 64;
    const int m0 = blockIdx.y * 64;
    const int arow = tid >> 2, acol = (tid & 3) << 2;
    const int bk = tid >> 4, bj = (tid & 15) << 2;

    float c[4][4] = {};
    for (int k0 = 0; k0 < K; k0 += 16) {
        __syncthreads();
        float4 av = *(const float4*)&A[(size_t)(m0 + arow) * K + k0 + acol];
        As[acol + 0][arow] = av.x;
        As[acol + 1][arow] = av.y;
        As[acol + 2][arow] = av.z;
        As[acol + 3][arow] = av.w;
        *(float4*)&Bs[bk][bj] = *(const float4*)&B[(size_t)(k0 + bk) * sh + j0 + bj];
        __syncthreads();
#pragma unroll
        for (int kk = 0; kk < 16; ++kk) {
            const float4 a = *(const float4*)&As[kk][ty << 2];
            const float4 b = *(const float4*)&Bs[kk][tx << 2];
            c[0][0] += a.x * b.x; c[0][1] += a.x * b.y; c[0][2] += a.x * b.z; c[0][3] += a.x * b.w;
            c[1][0] += a.y * b.x; c[1][1] += a.y * b.y; c[1][2] += a.y * b.z; c[1][3] += a.y * b.w;
            c[2][0] += a.z * b.x; c[2][1] += a.z * b.y; c[2][2] += a.z * b.z; c[2][3] += a.z * b.w;
            c[3][0] += a.w * b.x; c[3][1] += a.w * b.y; c[3][2] += a.w * b.z; c[3][3] += a.w * b.w;
        }
    }
    const float4 bv = *(const float4*)&bias[j0 + (tx << 2)];
#pragma unroll
    for (int i = 0; i < 4; ++i) {
        float4 o;
        o.x = c[i][0] + bv.x; o.y = c[i][1] + bv.y; o.z = c[i][2] + bv.z; o.w = c[i][3] + bv.w;
        if (relu) {
            o.x = fmaxf(o.x, 0.f); o.y = fmaxf(o.y, 0.f);
            o.z = fmaxf(o.z, 0.f); o.w = fmaxf(o.w, 0.f);
        }
        *(float4*)&C[(size_t)(m0 + (ty << 2) + i) * ldc + j0 + (tx << 2)] = o;
    }
}

// ---------------------------------------------------------------------------
// Weight conversions (one-time per launch)
// ---------------------------------------------------------------------------
// Big B'T[t][j(4352)][384]: j<4096 -> W2[t][j>>7][h][j&127]; <4224 -> b2; else root_w
__global__ void convb_big_k(const float* __restrict__ w2, const float* __restrict__ b2,
                            const float* __restrict__ rw, ushort* __restrict__ BT) {
    const int t = blockIdx.y;
    const int idx = blockIdx.x * 256 + threadIdx.x;   // 4352*128
    const int j = idx >> 7, h = idx & 127;
    float v;
    if (j < 4096)      v = w2[(size_t)t * 524288 + (size_t)(j >> 7) * 16384 + h * 128 + (j & 127)];
    else if (j < 4224) v = b2[t * 16384 + h * 128 + (j - 4096)];
    else               v = rw[t * 16384 + h * 128 + (j - 4224)];
    split3B(v, BT + (size_t)t * 1671168 + (size_t)j * 384, h);
}

// GRU weights: B[h][j] = w[j*128+h]  ->  BT[j][384]
__global__ void convb_gru_k(const float* __restrict__ wih, const float* __restrict__ whh,
                            ushort* __restrict__ BTih, ushort* __restrict__ BThh) {
    const int idx = blockIdx.x * 256 + threadIdx.x;   // 384*128
    const int j = idx >> 7, h = idx & 127;
    split3B(wih[idx], BTih + (size_t)j * 384, h);
    split3B(whh[idx], BThh + (size_t)j * 384, h);
}

__global__ void splita_k(const float* __restrict__ xh, ushort* __restrict__ Ax) {
    const int idx = blockIdx.x * 256 + threadIdx.x;   // 4096*128
    split3A(xh[idx], Ax + (size_t)(idx >> 7) * 384, idx & 127);
}

// ---------------------------------------------------------------------------
// Edge message + scatter: msg[e,o] = U[r,b2slice,o] + sum_k eh[e,k]*U[r,k,o]
// ---------------------------------------------------------------------------
__global__ __launch_bounds__(256) void edge_msg_k(
    const int* __restrict__ ei, const float* __restrict__ eattr,
    const float* __restrict__ w1, const float* __restrict__ b1,
    const float* __restrict__ U, float* __restrict__ agg)
{
    __shared__ float eh[2][32];
    const int half = threadIdx.x >> 7;
    const int o = threadIdx.x & 127;
    const int e = blockIdx.x * 2 + half;
    if (o < 32) {
        float v = eattr[e] * w1[o] + b1[o];
        eh[half][o] = v > 0.f ? v : 0.f;
    }
    __syncthreads();
    const int r = ei[e];
    const int c = ei[EE + e];
    const float* Ur = U + (size_t)r * ULD;
    float acc = Ur[4096 + o];
#pragma unroll
    for (int k = 0; k < 32; ++k) acc += eh[half][k] * Ur[k * 128 + o];
    atomicAdd(&agg[(size_t)c * 128 + o], acc);
}

__global__ void deg_k(const int* __restrict__ ei, float* __restrict__ deg) {
    int e = blockIdx.x * 256 + threadIdx.x;
    if (e < EE) atomicAdd(&deg[ei[EE + e]], 1.0f);
}
__global__ void invdeg_k(float* __restrict__ deg) {
    int n = blockIdx.x * 256 + threadIdx.x;
    if (n < NN) { float d = deg[n]; deg[n] = d > 0.f ? 1.0f / d : 0.0f; }
}

// m = relu(xr + agg*inv + conv_b); write split-bf16 A-rows directly
__global__ void mcomb_k(const float* __restrict__ bigC, const float* __restrict__ agg,
                        const float* __restrict__ inv, const float* __restrict__ cb,
                        ushort* __restrict__ Am) {
    const int idx = blockIdx.x * 256 + threadIdx.x;
    const int m = idx >> 7, c = idx & 127;
    float v = bigC[(size_t)m * ULD + 4224 + c] + agg[idx] * inv[m] + cb[c];
    v = v > 0.f ? v : 0.f;
    split3A(v, Am + (size_t)m * 384, c);
}

// GRU gate combine; writes fp32 xh and split-bf16 Ax for the next GEMMs
__global__ void gate_k(const float* __restrict__ G1, const float* __restrict__ G2,
                       float* __restrict__ xh, ushort* __restrict__ Ax) {
    const int idx = blockIdx.x * 256 + threadIdx.x;
    const int n = idx >> 7, o = idx & 127;
    const size_t b = (size_t)n * 384;
    float ir = G1[b + o], iz = G1[b + 128 + o], in_ = G1[b + 256 + o];
    float hr = G2[b + o], hz = G2[b + 128 + o], hn = G2[b + 256 + o];
    float r = 1.f / (1.f + expf(-(ir + hr)));
    float z = 1.f / (1.f + expf(-(iz + hz)));
    float nv = tanhf(in_ + r * hn);
    float hv = (1.f - z) * nv + z * xh[idx];
    xh[idx] = hv;
    split3A(hv, Ax + b, o);
}

__global__ void cnt_k(const int* __restrict__ batch, float* __restrict__ cnt) {
    __shared__ float loc[GG];
    if (threadIdx.x < GG) loc[threadIdx.x] = 0.f;
    __syncthreads();
    for (int n = threadIdx.x; n < NN; n += 256) atomicAdd(&loc[batch[n]], 1.0f);
    __syncthreads();
    if (threadIdx.x < GG) cnt[threadIdx.x] = loc[threadIdx.x];
}

__global__ __launch_bounds__(128) void pool_k(const int* __restrict__ batch,
                                              const float* __restrict__ xh,
                                              float* __restrict__ pooled) {
    const int o = threadIdx.x;
    const int n0 = blockIdx.x * 128;
    float acc = 0.f;
    int curg = batch[n0];
    for (int i = 0; i < 128; ++i) {
        int n = n0 + i;
        int g = batch[n];
        if (g != curg) {
            atomicAdd(&pooled[curg * 128 + o], acc);
            acc = 0.f; curg = g;
        }
        acc += xh[(size_t)n * 128 + o];
    }
    atomicAdd(&pooled[curg * 128 + o], acc);
}

__global__ __launch_bounds__(128) void final_k(
    const float* __restrict__ pooled, const float* __restrict__ cnt,
    const float* __restrict__ l1w, const float* __restrict__ l1b,
    const float* __restrict__ l2w, const float* __restrict__ l2b,
    float* __restrict__ out)
{
    __shared__ float gv[128];
    __shared__ float sy[64];
    const int t = threadIdx.x;
    for (int g = 0; g < GG; ++g) {
        float c = cnt[g]; c = c > 1.f ? c : 1.f;
        gv[t] = pooled[g * 128 + t] / c;
        __syncthreads();
        if (t < 64) {
            float y = l1b[t];
            for (int h = 0; h < 128; ++h) y += gv[h] * l1w[h * 64 + t];
            y = y > 0.f ? y : 0.f;
            sy[t] = y * l2w[t];
        }
        __syncthreads();
        if (t == 0) {
            float s = l2b[0];
            for (int j = 0; j < 64; ++j) s += sy[j];
            out[g] = s;
        }
        __syncthreads();
    }
}

extern "C" void kernel_launch(void* const* d_in, const int* in_sizes, int n_in,
                              void* d_out, int out_size, void* d_ws, size_t ws_size,
                              hipStream_t stream) {
    const float* x      = (const float*)d_in[0];
    const int*   ei     = (const int*)d_in[1];
    const float* eattr  = (const float*)d_in[2];
    const int*   batch  = (const int*)d_in[3];
    const float* lin0_w = (const float*)d_in[4];
    const float* lin0_b = (const float*)d_in[5];
    const float* nn_w1  = (const float*)d_in[6];
    const float* nn_b1  = (const float*)d_in[7];
    const float* nn_w2  = (const float*)d_in[8];
    const float* nn_b2  = (const float*)d_in[9];
    const float* root_w = (const float*)d_in[10];
    const float* conv_b = (const float*)d_in[11];
    const float* gwih   = (const float*)d_in[12];
    const float* gwhh   = (const float*)d_in[13];
    const float* gbih   = (const float*)d_in[14];
    const float* gbhh   = (const float*)d_in[15];
    const float* l1w    = (const float*)d_in[16];
    const float* l1b    = (const float*)d_in[17];
    const float* l2w    = (const float*)d_in[18];
    const float* l2b    = (const float*)d_in[19];
    float* out = (float*)d_out;
    float* ws  = (float*)d_ws;

    // workspace layout (float offsets)
    float*  xh     = ws;                          // [4096,128]
    float*  bigC   = ws + 524288;                 // [4096,4352]
    float*  agg    = ws + 18350080;               // [4096,128]
    float*  g1     = ws + 18874368;               // [4096,384]
    float*  g2     = ws + 20447232;               // [4096,384]
    float*  deg    = ws + 22020096;               // [4096]
    float*  pooled = ws + 22024192;               // [8,128]
    float*  cnt    = ws + 22025216;               // [8]
    ushort* Am     = (ushort*)(ws + 22025728);    // [4096,384] bf16
    ushort* Ax     = (ushort*)(ws + 22812160);    // [4096,384] bf16
    ushort* BTu    = (ushort*)(ws + 23598592);    // 3 x [4352,384] bf16
    ushort* BTwih  = (ushort*)(ws + 26105344);    // [384,384] bf16
    ushort* BTwhh  = (ushort*)(ws + 26179072);    // [384,384] bf16

    // one-time weight splits
    convb_big_k<<<dim3(2176, 3), 256, 0, stream>>>(nn_w2, nn_b2, root_w, BTu);
    convb_gru_k<<<192, 256, 0, stream>>>(gwih, gwhh, BTwih, BTwhh);

    // x0 = relu(x @ lin0_w + lin0_b)  (fp32, tiny) ; then split
    gemm_k<<<dim3(2, 64), 256, 0, stream>>>(x, 64, lin0_w, 128, lin0_b, xh, 128, 1);
    splita_k<<<2048, 256, 0, stream>>>(xh, Ax);

    hipMemsetAsync(deg, 0, NN * sizeof(float), stream);
    deg_k<<<EE / 256, 256, 0, stream>>>(ei, deg);
    invdeg_k<<<NN / 256, 256, 0, stream>>>(deg);

    for (int t = 0; t < 3; ++t) {
        // bigC = x @ [W2 | b2 | root_w]   (split-bf16 MFMA, N=4352)
        mgemm_k<<<dim3(34, 32, 1), 256, 0, stream>>>(
            Ax, BTu + (size_t)t * 1671168, nullptr, bigC, ULD,
            nullptr, nullptr, nullptr, nullptr, 0);

        hipMemsetAsync(agg, 0, (size_t)NN * HH * sizeof(float), stream);
        edge_msg_k<<<EE / 2, 256, 0, stream>>>(ei, eattr, nn_w1 + t * 32, nn_b1 + t * 32,
                                               bigC, agg);
        mcomb_k<<<2048, 256, 0, stream>>>(bigC, agg, deg, conv_b + t * 128, Am);

        // both GRU GEMMs in one dispatch (z=0: g1 = m@wihT+bih, z=1: g2 = h@whhT+bhh)
        mgemm_k<<<dim3(3, 32, 2), 256, 0, stream>>>(
            Am, BTwih, gbih, g1, 384,
            Ax, BTwhh, gbhh, g2, 384);
        gate_k<<<2048, 256, 0, stream>>>(g1, g2, xh, Ax);
    }

    hipMemsetAsync(pooled, 0, GG * HH * sizeof(float), stream);
    cnt_k<<<1, 256, 0, stream>>>(batch, cnt);
    pool_k<<<NN / 128, 128, 0, stream>>>(batch, xh, pooled);
    final_k<<<1, 128, 0, stream>>>(pooled, cnt, l1w, l1b, l2w, l2b, out);
}

// Round 3
// 359.286 us; speedup vs baseline: 1.6510x; 1.1495x over previous
//
#include <hip/hip_runtime.h>
#include <math.h>

#define NN 4096
#define EE 8192
#define HH 128
#define GG 8
#define ULD 4352          // big GEMM cols: 4096 (W2) + 128 (b2) + 128 (root)
#define KSP 384           // split-bf16 K: [Ah|Ah|Al] x [Bh|Bl|Bh]

typedef __attribute__((ext_vector_type(8))) short short8;
typedef __attribute__((ext_vector_type(4))) float floatx4;

__device__ __forceinline__ ushort rne_bf16(float v) {
    unsigned u = __float_as_uint(v);
    return (ushort)((u + 0x7fffu + ((u >> 16) & 1u)) >> 16);
}
__device__ __forceinline__ float bf16_f(ushort h) {
    return __uint_as_float(((unsigned)h) << 16);
}
// A-side 384-row: [hi, hi, lo]
__device__ __forceinline__ void split3A(float v, ushort* base, int c) {
    ushort hi = rne_bf16(v);
    ushort lo = rne_bf16(v - bf16_f(hi));
    base[c] = hi; base[128 + c] = hi; base[256 + c] = lo;
}
// B-side 384-row: [hi, lo, hi]
__device__ __forceinline__ void split3B(float v, ushort* base, int h) {
    ushort hi = rne_bf16(v);
    ushort lo = rne_bf16(v - bf16_f(hi));
    base[h] = hi; base[128 + h] = lo; base[256 + h] = hi;
}

__device__ __forceinline__ void ldst16(const ushort* g, void* l) {
    __builtin_amdgcn_global_load_lds(
        (const __attribute__((address_space(1))) unsigned int*)g,
        (__attribute__((address_space(3))) unsigned int*)l, 16, 0, 0);
}

// ---------------------------------------------------------------------------
// Split-bf16 MFMA GEMM: C[M,ldc] = A'[M,384] @ B'T[N,384]^T (+bias[col])
// 128x128 tile/block, 4 waves (2x2 of 64x64), BK=32.
// cfp16: store C as _Float16. blockIdx.z selects operand set.
// ---------------------------------------------------------------------------
__global__ __launch_bounds__(256) void mgemm_k(
    const ushort* __restrict__ A0, const ushort* __restrict__ B0,
    const float* __restrict__ bias0, void* __restrict__ C0, int ldc0, int h0,
    const ushort* __restrict__ A1, const ushort* __restrict__ B1,
    const float* __restrict__ bias1, void* __restrict__ C1, int ldc1, int h1)
{
    const ushort* A = A0; const ushort* B = B0; const float* bias = bias0;
    void* C = C0; int ldc = ldc0; int cfp16 = h0;
    if (blockIdx.z == 1) { A = A1; B = B1; bias = bias1; C = C1; ldc = ldc1; cfp16 = h1; }

    __shared__ __align__(16) ushort As[128 * 32];  // [row][k]
    __shared__ __align__(16) ushort Bs[128 * 32];  // [col][k]
    const int tid = threadIdx.x;
    const int lane = tid & 63, wave = tid >> 6;
    const int m0 = blockIdx.y * 128, n0 = blockIdx.x * 128;
    const int wr = (wave >> 1) * 64, wc = (wave & 1) * 64;
    const int fm = lane & 15, fq = lane >> 4;

    const int srow = tid >> 2, soff = (tid & 3) << 3;
    const ushort* gA0 = A + (size_t)(m0 + srow) * KSP + soff;
    const ushort* gA1 = gA0 + (size_t)64 * KSP;
    const ushort* gB0 = B + (size_t)(n0 + srow) * KSP + soff;
    const ushort* gB1 = gB0 + (size_t)64 * KSP;
    char* lA0 = (char*)As + tid * 16;  char* lA1 = (char*)As + (tid + 256) * 16;
    char* lB0 = (char*)Bs + tid * 16;  char* lB1 = (char*)Bs + (tid + 256) * 16;

    floatx4 acc[4][4] = {};
    for (int k0 = 0; k0 < KSP; k0 += 32) {
        __syncthreads();
        ldst16(gA0 + k0, lA0); ldst16(gA1 + k0, lA1);
        ldst16(gB0 + k0, lB0); ldst16(gB1 + k0, lB1);
        __syncthreads();
        short8 af[4], bf[4];
#pragma unroll
        for (int i = 0; i < 4; ++i)
            af[i] = *(const short8*)&As[(wr + i * 16 + fm) * 32 + fq * 8];
#pragma unroll
        for (int j = 0; j < 4; ++j)
            bf[j] = *(const short8*)&Bs[(wc + j * 16 + fm) * 32 + fq * 8];
#pragma unroll
        for (int i = 0; i < 4; ++i)
#pragma unroll
            for (int j = 0; j < 4; ++j)
                acc[i][j] = __builtin_amdgcn_mfma_f32_16x16x32_bf16(
                    af[i], bf[j], acc[i][j], 0, 0, 0);
    }
    // C/D layout: col = lane&15, row = (lane>>4)*4 + reg  [m89-verified]
    const int er = fq * 4, ec = fm;
#pragma unroll
    for (int i = 0; i < 4; ++i) {
        const int gr = m0 + wr + i * 16 + er;
#pragma unroll
        for (int j = 0; j < 4; ++j) {
            const int gc = n0 + wc + j * 16 + ec;
            const float bv = bias ? bias[gc] : 0.0f;
#pragma unroll
            for (int r = 0; r < 4; ++r) {
                const float v = acc[i][j][r] + bv;
                if (cfp16) ((_Float16*)C)[(size_t)(gr + r) * ldc + gc] = (_Float16)v;
                else       ((float*)C)[(size_t)(gr + r) * ldc + gc] = v;
            }
        }
    }
}

// ---------------------------------------------------------------------------
// lin0: xh = relu(x[4096,64] @ w[64,128] + b); also writes split-bf16 Ax.
// grid dim3(2,64), 256 threads.
// ---------------------------------------------------------------------------
__global__ __launch_bounds__(256) void lin0_k(
    const float* __restrict__ Ag, const float* __restrict__ Bg,
    const float* __restrict__ bias, float* __restrict__ xh,
    ushort* __restrict__ Ax)
{
    __shared__ float As[16][64];
    __shared__ float Bs[16][64];
    const int tid = threadIdx.x;
    const int tx = tid & 15, ty = tid >> 4;
    const int j0 = blockIdx.x * 64;
    const int m0 = blockIdx.y * 64;
    const int arow = tid >> 2, acol = (tid & 3) << 2;
    const int bk = tid >> 4, bj = (tid & 15) << 2;

    float c[4][4] = {};
    for (int k0 = 0; k0 < 64; k0 += 16) {
        __syncthreads();
        float4 av = *(const float4*)&Ag[(size_t)(m0 + arow) * 64 + k0 + acol];
        As[acol + 0][arow] = av.x;
        As[acol + 1][arow] = av.y;
        As[acol + 2][arow] = av.z;
        As[acol + 3][arow] = av.w;
        *(float4*)&Bs[bk][bj] = *(const float4*)&Bg[(size_t)(k0 + bk) * 128 + j0 + bj];
        __syncthreads();
#pragma unroll
        for (int kk = 0; kk < 16; ++kk) {
            const float4 a = *(const float4*)&As[kk][ty << 2];
            const float4 b = *(const float4*)&Bs[kk][tx << 2];
            c[0][0] += a.x * b.x; c[0][1] += a.x * b.y; c[0][2] += a.x * b.z; c[0][3] += a.x * b.w;
            c[1][0] += a.y * b.x; c[1][1] += a.y * b.y; c[1][2] += a.y * b.z; c[1][3] += a.y * b.w;
            c[2][0] += a.z * b.x; c[2][1] += a.z * b.y; c[2][2] += a.z * b.z; c[2][3] += a.z * b.w;
            c[3][0] += a.w * b.x; c[3][1] += a.w * b.y; c[3][2] += a.w * b.z; c[3][3] += a.w * b.w;
        }
    }
    const float4 bv = *(const float4*)&bias[j0 + (tx << 2)];
    const int col0 = j0 + (tx << 2);
#pragma unroll
    for (int i = 0; i < 4; ++i) {
        const int row = m0 + (ty << 2) + i;
        float4 o;
        o.x = fmaxf(c[i][0] + bv.x, 0.f); o.y = fmaxf(c[i][1] + bv.y, 0.f);
        o.z = fmaxf(c[i][2] + bv.z, 0.f); o.w = fmaxf(c[i][3] + bv.w, 0.f);
        *(float4*)&xh[(size_t)row * 128 + col0] = o;
        ushort* base = Ax + (size_t)row * 384;
        split3A(o.x, base, col0 + 0);
        split3A(o.y, base, col0 + 1);
        split3A(o.z, base, col0 + 2);
        split3A(o.w, base, col0 + 3);
    }
}

// ---------------------------------------------------------------------------
// One-time setup: GRU weight split + degree/out-degree/graph-count histograms
// grid: 240 blocks x 256
// ---------------------------------------------------------------------------
__global__ __launch_bounds__(256) void setup_k(
    const float* __restrict__ wih, const float* __restrict__ whh,
    ushort* __restrict__ BTih, ushort* __restrict__ BThh,
    const int* __restrict__ ei, const int* __restrict__ batch,
    float* __restrict__ deg, int* __restrict__ odeg, float* __restrict__ cnt)
{
    __shared__ float loc8[GG];
    const int b = blockIdx.x, t = threadIdx.x;
    if (b < 192) {
        const int idx = b * 256 + t;           // 384*128
        const int j = idx >> 7, h = idx & 127;
        split3B(wih[idx], BTih + (size_t)j * 384, h);
        split3B(whh[idx], BThh + (size_t)j * 384, h);
    } else if (b < 224) {
        const int e = (b - 192) * 256 + t;     // 8192
        atomicAdd(&deg[ei[EE + e]], 1.0f);
        atomicAdd(&odeg[ei[e]], 1);
    } else {
        const int n = (b - 224) * 256 + t;     // 4096
        if (t < GG) loc8[t] = 0.f;
        __syncthreads();
        atomicAdd(&loc8[batch[n]], 1.0f);
        __syncthreads();
        if (t < GG) atomicAdd(&cnt[t], loc8[t]);
    }
}

// exclusive prefix sum of odeg[4096] -> ocur (single block)
__global__ __launch_bounds__(256) void scan_k(const int* __restrict__ odeg,
                                              int* __restrict__ ocur) {
    __shared__ int ps[256];
    const int t = threadIdx.x;
    const int base = t * 16;
    int l[16]; int s = 0;
#pragma unroll
    for (int i = 0; i < 16; ++i) { l[i] = s; s += odeg[base + i]; }
    ps[t] = s;
    __syncthreads();
    for (int d = 1; d < 256; d <<= 1) {
        int v = (t >= d) ? ps[t - d] : 0;
        __syncthreads();
        ps[t] += v;
        __syncthreads();
    }
    const int excl = (t == 0) ? 0 : ps[t - 1];
#pragma unroll
    for (int i = 0; i < 16; ++i) ocur[base + i] = excl + l[i];
}

__global__ void scatter_k(const int* __restrict__ ei, int* __restrict__ ocur,
                          int* __restrict__ perm) {
    const int e = blockIdx.x * 256 + threadIdx.x;
    const int pos = atomicAdd(&ocur[ei[e]], 1);
    perm[pos] = e;
}

// ---------------------------------------------------------------------------
// Edge message + scatter, source-sorted order via perm, fp16 U.
// msg[e,o] = U[r,b2,o] + sum_k eh[e,k]*U[r,k,o]; atomicAdd into agg[c,o].
// ---------------------------------------------------------------------------
__global__ __launch_bounds__(256) void edge_msg_k(
    const int* __restrict__ ei, const int* __restrict__ perm,
    const float* __restrict__ eattr,
    const float* __restrict__ w1, const float* __restrict__ b1,
    const _Float16* __restrict__ U, float* __restrict__ agg)
{
    __shared__ float eh[2][32];
    const int b = blockIdx.x;                      // 4096 pairs
    const int p = (b & 7) * 512 + (b >> 3);        // XCD-contiguous sorted ranges
    const int half = threadIdx.x >> 7;
    const int o = threadIdx.x & 127;
    const int e = perm[p * 2 + half];
    if (o < 32) {
        float v = eattr[e] * w1[o] + b1[o];
        eh[half][o] = v > 0.f ? v : 0.f;
    }
    __syncthreads();
    const int r = ei[e];
    const int c = ei[EE + e];
    const _Float16* Ur = U + (size_t)r * ULD;
    float acc = (float)Ur[4096 + o];
#pragma unroll
    for (int k = 0; k < 32; ++k) acc += eh[half][k] * (float)Ur[k * 128 + o];
    atomicAdd(&agg[(size_t)c * 128 + o], acc);
}

// m = relu(root + agg/deg + conv_b); write split-bf16 A-rows
__global__ void mcomb_k(const _Float16* __restrict__ bigC, const float* __restrict__ agg,
                        const float* __restrict__ deg, const float* __restrict__ cb,
                        ushort* __restrict__ Am) {
    const int idx = blockIdx.x * 256 + threadIdx.x;
    const int m = idx >> 7, c = idx & 127;
    const float d = deg[m];
    const float inv = d > 0.f ? 1.0f / d : 0.0f;
    float v = (float)bigC[(size_t)m * ULD + 4224 + c] + agg[idx] * inv + cb[c];
    v = v > 0.f ? v : 0.f;
    split3A(v, Am + (size_t)m * 384, c);
}

// GRU gate combine; updates xh + split Ax; optional fused pooling (last step)
__global__ void gate_k(const float* __restrict__ G1, const float* __restrict__ G2,
                       float* __restrict__ xh, ushort* __restrict__ Ax,
                       const int* __restrict__ batch, float* __restrict__ pooled) {
    const int idx = blockIdx.x * 256 + threadIdx.x;
    const int n = idx >> 7, o = idx & 127;
    const size_t b = (size_t)n * 384;
    float ir = G1[b + o], iz = G1[b + 128 + o], in_ = G1[b + 256 + o];
    float hr = G2[b + o], hz = G2[b + 128 + o], hn = G2[b + 256 + o];
    float r = 1.f / (1.f + expf(-(ir + hr)));
    float z = 1.f / (1.f + expf(-(iz + hz)));
    float nv = tanhf(in_ + r * hn);
    float hv = (1.f - z) * nv + z * xh[idx];
    xh[idx] = hv;
    split3A(hv, Ax + b, o);
    if (pooled) atomicAdd(&pooled[batch[n] * 128 + o], hv);
}

// Big B'T[t][j(4352)][384]
__global__ void convb_big_k(const float* __restrict__ w2, const float* __restrict__ b2,
                            const float* __restrict__ rw, ushort* __restrict__ BT) {
    const int t = blockIdx.y;
    const int idx = blockIdx.x * 256 + threadIdx.x;   // 4352*128
    const int j = idx >> 7, h = idx & 127;
    float v;
    if (j < 4096)      v = w2[(size_t)t * 524288 + (size_t)(j >> 7) * 16384 + h * 128 + (j & 127)];
    else if (j < 4224) v = b2[t * 16384 + h * 128 + (j - 4096)];
    else               v = rw[t * 16384 + h * 128 + (j - 4224)];
    split3B(v, BT + (size_t)t * 1671168 + (size_t)j * 384, h);
}

__global__ __launch_bounds__(128) void final_k(
    const float* __restrict__ pooled, const float* __restrict__ cnt,
    const float* __restrict__ l1w, const float* __restrict__ l1b,
    const float* __restrict__ l2w, const float* __restrict__ l2b,
    float* __restrict__ out)
{
    __shared__ float gv[128];
    __shared__ float sy[64];
    const int t = threadIdx.x;
    for (int g = 0; g < GG; ++g) {
        float c = cnt[g]; c = c > 1.f ? c : 1.f;
        gv[t] = pooled[g * 128 + t] / c;
        __syncthreads();
        if (t < 64) {
            float y = l1b[t];
            for (int h = 0; h < 128; ++h) y += gv[h] * l1w[h * 64 + t];
            y = y > 0.f ? y : 0.f;
            sy[t] = y * l2w[t];
        }
        __syncthreads();
        if (t == 0) {
            float s = l2b[0];
            for (int j = 0; j < 64; ++j) s += sy[j];
            out[g] = s;
        }
        __syncthreads();
    }
}

extern "C" void kernel_launch(void* const* d_in, const int* in_sizes, int n_in,
                              void* d_out, int out_size, void* d_ws, size_t ws_size,
                              hipStream_t stream) {
    const float* x      = (const float*)d_in[0];
    const int*   ei     = (const int*)d_in[1];
    const float* eattr  = (const float*)d_in[2];
    const int*   batch  = (const int*)d_in[3];
    const float* lin0_w = (const float*)d_in[4];
    const float* lin0_b = (const float*)d_in[5];
    const float* nn_w1  = (const float*)d_in[6];
    const float* nn_b1  = (const float*)d_in[7];
    const float* nn_w2  = (const float*)d_in[8];
    const float* nn_b2  = (const float*)d_in[9];
    const float* root_w = (const float*)d_in[10];
    const float* conv_b = (const float*)d_in[11];
    const float* gwih   = (const float*)d_in[12];
    const float* gwhh   = (const float*)d_in[13];
    const float* gbih   = (const float*)d_in[14];
    const float* gbhh   = (const float*)d_in[15];
    const float* l1w    = (const float*)d_in[16];
    const float* l1b    = (const float*)d_in[17];
    const float* l2w    = (const float*)d_in[18];
    const float* l2b    = (const float*)d_in[19];
    float* out = (float*)d_out;
    float* ws  = (float*)d_ws;

    // ---- workspace layout (float offsets; zero region first, contiguous) ----
    float*  agg0   = ws;                          // 3 x [4096,128]
    float*  pooled = ws + 1572864;                // [8,128]
    float*  cnt    = ws + 1573888;                // [8]
    float*  deg    = ws + 1573896;                // [4096]
    int*    odeg   = (int*)(ws + 1577992);        // [4096]
    // end of zero region: 1582088 floats = 6328352 bytes
    int*    ocur   = (int*)(ws + 1582088);        // [4096]
    int*    perm   = (int*)(ws + 1586184);        // [8192]
    float*  xh     = ws + 1594376;                // [4096,128]
    float*  g1     = ws + 2118664;                // [4096,384]
    float*  g2     = ws + 3691528;                // [4096,384]
    _Float16* bigC = (_Float16*)(ws + 5264392);   // [4096,4352] fp16
    ushort* Am     = (ushort*)(ws + 14177288);    // [4096,384] bf16
    ushort* Ax     = (ushort*)(ws + 14963720);    // [4096,384] bf16
    ushort* BTu    = (ushort*)(ws + 15750152);    // 3 x [4352,384] bf16
    ushort* BTwih  = (ushort*)(ws + 18256904);    // [384,384] bf16
    ushort* BTwhh  = (ushort*)(ws + 18330632);    // [384,384] bf16

    hipMemsetAsync(agg0, 0, 6328352, stream);
    convb_big_k<<<dim3(2176, 3), 256, 0, stream>>>(nn_w2, nn_b2, root_w, BTu);
    setup_k<<<240, 256, 0, stream>>>(gwih, gwhh, BTwih, BTwhh, ei, batch, deg, odeg, cnt);
    scan_k<<<1, 256, 0, stream>>>(odeg, ocur);
    scatter_k<<<EE / 256, 256, 0, stream>>>(ei, ocur, perm);
    lin0_k<<<dim3(2, 64), 256, 0, stream>>>(x, lin0_w, lin0_b, xh, Ax);

    for (int t = 0; t < 3; ++t) {
        float* agg = agg0 + (size_t)t * 524288;
        // bigC = x @ [W2 | b2 | root_w]   (split-bf16 MFMA, fp16 out)
        mgemm_k<<<dim3(34, 32, 1), 256, 0, stream>>>(
            Ax, BTu + (size_t)t * 1671168, nullptr, bigC, ULD, 1,
            nullptr, nullptr, nullptr, nullptr, 0, 0);
        edge_msg_k<<<EE / 2, 256, 0, stream>>>(ei, perm, eattr,
                                               nn_w1 + t * 32, nn_b1 + t * 32, bigC, agg);
        mcomb_k<<<2048, 256, 0, stream>>>(bigC, agg, deg, conv_b + t * 128, Am);
        // both GRU GEMMs in one dispatch
        mgemm_k<<<dim3(3, 32, 2), 256, 0, stream>>>(
            Am, BTwih, gbih, g1, 384, 0,
            Ax, BTwhh, gbhh, g2, 384, 0);
        gate_k<<<2048, 256, 0, stream>>>(g1, g2, xh, Ax, batch,
                                         (t == 2) ? pooled : nullptr);
    }

    final_k<<<1, 128, 0, stream>>>(pooled, cnt, l1w, l1b, l2w, l2b, out);
}

// Round 4
// 282.561 us; speedup vs baseline: 2.0993x; 1.2715x over previous
//
#include <hip/hip_runtime.h>
#include <math.h>

#define NN 4096
#define EE 8192
#define HH 128
#define GG 8
#define ULD 4352          // big GEMM cols: 4096 (W2) + 128 (b2) + 128 (root)

typedef __attribute__((ext_vector_type(8))) _Float16 half8;
typedef __attribute__((ext_vector_type(4))) float floatx4;

__device__ __forceinline__ void ldst16(const _Float16* g, void* l) {
    __builtin_amdgcn_global_load_lds(
        (const __attribute__((address_space(1))) unsigned int*)g,
        (__attribute__((address_space(3))) unsigned int*)l, 16, 0, 0);
}

// ---------------------------------------------------------------------------
// fp16 MFMA GEMM: C[M,ULD] = A[M,128] @ BT[N,128]^T, C stored fp16.
// 128x128 tile/block, 4 waves (2x2 of 64x64), BK=32, K=128 (4 iters).
// Structure identical to the verified split-bf16 kernel (R1/R2), dtype fp16.
// ---------------------------------------------------------------------------
__global__ __launch_bounds__(256) void mgemm16_k(
    const _Float16* __restrict__ A, const _Float16* __restrict__ B,
    _Float16* __restrict__ C)
{
    __shared__ __align__(16) _Float16 As[128 * 32];  // [row][k]
    __shared__ __align__(16) _Float16 Bs[128 * 32];  // [col][k]
    const int tid = threadIdx.x;
    const int lane = tid & 63, wave = tid >> 6;
    const int m0 = blockIdx.y * 128, n0 = blockIdx.x * 128;
    const int wr = (wave >> 1) * 64, wc = (wave & 1) * 64;
    const int fm = lane & 15, fq = lane >> 4;

    const int srow = tid >> 2, soff = (tid & 3) << 3;
    const _Float16* gA0 = A + (size_t)(m0 + srow) * 128 + soff;
    const _Float16* gA1 = gA0 + (size_t)64 * 128;
    const _Float16* gB0 = B + (size_t)(n0 + srow) * 128 + soff;
    const _Float16* gB1 = gB0 + (size_t)64 * 128;
    char* lA0 = (char*)As + tid * 16;  char* lA1 = (char*)As + (tid + 256) * 16;
    char* lB0 = (char*)Bs + tid * 16;  char* lB1 = (char*)Bs + (tid + 256) * 16;

    floatx4 acc[4][4] = {};
    for (int k0 = 0; k0 < 128; k0 += 32) {
        __syncthreads();
        ldst16(gA0 + k0, lA0); ldst16(gA1 + k0, lA1);
        ldst16(gB0 + k0, lB0); ldst16(gB1 + k0, lB1);
        __syncthreads();
        half8 af[4], bf[4];
#pragma unroll
        for (int i = 0; i < 4; ++i)
            af[i] = *(const half8*)&As[(wr + i * 16 + fm) * 32 + fq * 8];
#pragma unroll
        for (int j = 0; j < 4; ++j)
            bf[j] = *(const half8*)&Bs[(wc + j * 16 + fm) * 32 + fq * 8];
#pragma unroll
        for (int i = 0; i < 4; ++i)
#pragma unroll
            for (int j = 0; j < 4; ++j)
                acc[i][j] = __builtin_amdgcn_mfma_f32_16x16x32_f16(
                    af[i], bf[j], acc[i][j], 0, 0, 0);
    }
    // C/D layout: col = lane&15, row = (lane>>4)*4 + reg  [m89; dtype-indep]
    const int er = fq * 4, ec = fm;
#pragma unroll
    for (int i = 0; i < 4; ++i) {
        const int gr = m0 + wr + i * 16 + er;
#pragma unroll
        for (int j = 0; j < 4; ++j) {
            const int gc = n0 + wc + j * 16 + ec;
#pragma unroll
            for (int r = 0; r < 4; ++r)
                C[(size_t)(gr + r) * ULD + gc] = (_Float16)acc[i][j][r];
        }
    }
}

// ---------------------------------------------------------------------------
// GRU GEMM, both gates in one dispatch via blockIdx.z, with mcomb fused into
// the z=0 A-staging: A(z=0) = m = relu(bigC_root + agg + conv_b), fp16.
// A(z=1) = Ax (h as fp16). B rows = weight rows (K=128). C fp32 [4096,384].
// LDS padded to 40 halves/row (80B stride -> conflict-free ds_read_b128).
// ---------------------------------------------------------------------------
__global__ __launch_bounds__(256) void gru_k(
    const _Float16* __restrict__ bigC, const float* __restrict__ agg,
    const float* __restrict__ cb, const _Float16* __restrict__ Ax,
    const _Float16* __restrict__ Bih, const _Float16* __restrict__ Bhh,
    const float* __restrict__ bih, const float* __restrict__ bhh,
    float* __restrict__ g1, float* __restrict__ g2)
{
    const int z = blockIdx.z;
    const _Float16* B = z ? Bhh : Bih;
    const float* bias = z ? bhh : bih;
    float* C = z ? g2 : g1;

    __shared__ __align__(16) _Float16 As[128 * 40];
    __shared__ __align__(16) _Float16 Bs[128 * 40];
    const int tid = threadIdx.x;
    const int lane = tid & 63, wave = tid >> 6;
    const int m0 = blockIdx.y * 128, n0 = blockIdx.x * 128;
    const int wr = (wave >> 1) * 64, wc = (wave & 1) * 64;
    const int fm = lane & 15, fq = lane >> 4;

    floatx4 acc[4][4] = {};
    for (int k0 = 0; k0 < 128; k0 += 32) {
        __syncthreads();
#pragma unroll
        for (int c = tid; c < 512; c += 256) {
            const int row = c >> 2, seg = (c & 3) << 3;
            // stage A
            if (z == 0) {
                const int mr = m0 + row;
                _Float16 v8[8];
#pragma unroll
                for (int u = 0; u < 8; ++u) {
                    const int cc = k0 + seg + u;
                    float v = (float)bigC[(size_t)mr * ULD + 4224 + cc]
                              + agg[(size_t)mr * 128 + cc] + cb[cc];
                    v8[u] = (_Float16)(v > 0.f ? v : 0.f);
                }
                *(half8*)&As[row * 40 + seg] = *(half8*)v8;
            } else {
                *(half8*)&As[row * 40 + seg] =
                    *(const half8*)&Ax[(size_t)(m0 + row) * 128 + k0 + seg];
            }
            // stage B
            *(half8*)&Bs[row * 40 + seg] =
                *(const half8*)&B[(size_t)(n0 + row) * 128 + k0 + seg];
        }
        __syncthreads();
        half8 af[4], bf[4];
#pragma unroll
        for (int i = 0; i < 4; ++i)
            af[i] = *(const half8*)&As[(wr + i * 16 + fm) * 40 + fq * 8];
#pragma unroll
        for (int j = 0; j < 4; ++j)
            bf[j] = *(const half8*)&Bs[(wc + j * 16 + fm) * 40 + fq * 8];
#pragma unroll
        for (int i = 0; i < 4; ++i)
#pragma unroll
            for (int j = 0; j < 4; ++j)
                acc[i][j] = __builtin_amdgcn_mfma_f32_16x16x32_f16(
                    af[i], bf[j], acc[i][j], 0, 0, 0);
    }
    const int er = fq * 4, ec = fm;
#pragma unroll
    for (int i = 0; i < 4; ++i) {
        const int gr = m0 + wr + i * 16 + er;
#pragma unroll
        for (int j = 0; j < 4; ++j) {
            const int gc = n0 + wc + j * 16 + ec;
            const float bv = bias[gc];
#pragma unroll
            for (int r = 0; r < 4; ++r)
                C[(size_t)(gr + r) * 384 + gc] = acc[i][j][r] + bv;
        }
    }
}

// ---------------------------------------------------------------------------
// lin0: xh = relu(x[4096,64] @ w[64,128] + b) fp32; also writes Ax fp16.
// ---------------------------------------------------------------------------
__global__ __launch_bounds__(256) void lin0_k(
    const float* __restrict__ Ag, const float* __restrict__ Bg,
    const float* __restrict__ bias, float* __restrict__ xh,
    _Float16* __restrict__ Ax)
{
    __shared__ float As[16][64];
    __shared__ float Bs[16][64];
    const int tid = threadIdx.x;
    const int tx = tid & 15, ty = tid >> 4;
    const int j0 = blockIdx.x * 64;
    const int m0 = blockIdx.y * 64;
    const int arow = tid >> 2, acol = (tid & 3) << 2;
    const int bk = tid >> 4, bj = (tid & 15) << 2;

    float c[4][4] = {};
    for (int k0 = 0; k0 < 64; k0 += 16) {
        __syncthreads();
        float4 av = *(const float4*)&Ag[(size_t)(m0 + arow) * 64 + k0 + acol];
        As[acol + 0][arow] = av.x;
        As[acol + 1][arow] = av.y;
        As[acol + 2][arow] = av.z;
        As[acol + 3][arow] = av.w;
        *(float4*)&Bs[bk][bj] = *(const float4*)&Bg[(size_t)(k0 + bk) * 128 + j0 + bj];
        __syncthreads();
#pragma unroll
        for (int kk = 0; kk < 16; ++kk) {
            const float4 a = *(const float4*)&As[kk][ty << 2];
            const float4 b = *(const float4*)&Bs[kk][tx << 2];
            c[0][0] += a.x * b.x; c[0][1] += a.x * b.y; c[0][2] += a.x * b.z; c[0][3] += a.x * b.w;
            c[1][0] += a.y * b.x; c[1][1] += a.y * b.y; c[1][2] += a.y * b.z; c[1][3] += a.y * b.w;
            c[2][0] += a.z * b.x; c[2][1] += a.z * b.y; c[2][2] += a.z * b.z; c[2][3] += a.z * b.w;
            c[3][0] += a.w * b.x; c[3][1] += a.w * b.y; c[3][2] += a.w * b.z; c[3][3] += a.w * b.w;
        }
    }
    const float4 bv = *(const float4*)&bias[j0 + (tx << 2)];
    const int col0 = j0 + (tx << 2);
#pragma unroll
    for (int i = 0; i < 4; ++i) {
        const int row = m0 + (ty << 2) + i;
        float4 o;
        o.x = fmaxf(c[i][0] + bv.x, 0.f); o.y = fmaxf(c[i][1] + bv.y, 0.f);
        o.z = fmaxf(c[i][2] + bv.z, 0.f); o.w = fmaxf(c[i][3] + bv.w, 0.f);
        *(float4*)&xh[(size_t)row * 128 + col0] = o;
        _Float16* base = Ax + (size_t)row * 128 + col0;
        base[0] = (_Float16)o.x; base[1] = (_Float16)o.y;
        base[2] = (_Float16)o.z; base[3] = (_Float16)o.w;
    }
}

// ---------------------------------------------------------------------------
// setup: GRU weight fp32->fp16 cast + degree/out-degree/graph-count hists
// ---------------------------------------------------------------------------
__global__ __launch_bounds__(256) void setup_k(
    const float* __restrict__ wih, const float* __restrict__ whh,
    _Float16* __restrict__ Bih, _Float16* __restrict__ Bhh,
    const int* __restrict__ ei, const int* __restrict__ batch,
    float* __restrict__ deg, int* __restrict__ odeg, float* __restrict__ cnt)
{
    __shared__ float loc8[GG];
    const int b = blockIdx.x, t = threadIdx.x;
    if (b < 192) {
        const int idx = b * 256 + t;           // 384*128
        Bih[idx] = (_Float16)wih[idx];
        Bhh[idx] = (_Float16)whh[idx];
    } else if (b < 224) {
        const int e = (b - 192) * 256 + t;     // 8192
        atomicAdd(&deg[ei[EE + e]], 1.0f);
        atomicAdd(&odeg[ei[e]], 1);
    } else {
        const int n = (b - 224) * 256 + t;     // 4096
        if (t < GG) loc8[t] = 0.f;
        __syncthreads();
        atomicAdd(&loc8[batch[n]], 1.0f);
        __syncthreads();
        if (t < GG) atomicAdd(&cnt[t], loc8[t]);
    }
}

// exclusive prefix sum of odeg[4096] -> ocur (single block)
__global__ __launch_bounds__(256) void scan_k(const int* __restrict__ odeg,
                                              int* __restrict__ ocur) {
    __shared__ int ps[256];
    const int t = threadIdx.x;
    const int base = t * 16;
    int l[16]; int s = 0;
#pragma unroll
    for (int i = 0; i < 16; ++i) { l[i] = s; s += odeg[base + i]; }
    ps[t] = s;
    __syncthreads();
    for (int d = 1; d < 256; d <<= 1) {
        int v = (t >= d) ? ps[t - d] : 0;
        __syncthreads();
        ps[t] += v;
        __syncthreads();
    }
    const int excl = (t == 0) ? 0 : ps[t - 1];
#pragma unroll
    for (int i = 0; i < 16; ++i) ocur[base + i] = excl + l[i];
}

// counting-sort scatter by source + precompute per-edge tables in sorted order:
// rc[pos] = (row, col); ehP[t][pos][k<32] = relu(ea*w1+b1)*inv_deg(col),
// ehP[t][pos][32] = inv_deg(col)   (coefficient of the b2/U-bias slice)
__global__ void scatter_k(const int* __restrict__ ei, const float* __restrict__ eattr,
                          const float* __restrict__ w1, const float* __restrict__ b1,
                          const float* __restrict__ deg, int* __restrict__ ocur,
                          int2* __restrict__ rc, float* __restrict__ ehP) {
    const int e = blockIdx.x * 256 + threadIdx.x;
    const int r = ei[e], c = ei[EE + e];
    const int pos = atomicAdd(&ocur[r], 1);
    rc[pos] = make_int2(r, c);
    const float d = deg[c];
    const float inv = d > 0.f ? 1.0f / d : 0.0f;
    const float ea = eattr[e];
    for (int t = 0; t < 3; ++t) {
        float* dst = ehP + ((size_t)t * EE + pos) * 33;
        for (int k = 0; k < 32; ++k) {
            float v = ea * w1[t * 32 + k] + b1[t * 32 + k];
            dst[k] = (v > 0.f ? v : 0.f) * inv;
        }
        dst[32] = inv;
    }
}

// ---------------------------------------------------------------------------
// Edge gather + scatter (pure): acc = ehP[32]*U[r,b2,o] + sum_k ehP[k]*U[r,k,o]
// ---------------------------------------------------------------------------
__global__ __launch_bounds__(256) void edge_msg_k(
    const int2* __restrict__ rc, const float* __restrict__ ehP,
    const _Float16* __restrict__ U, float* __restrict__ agg)
{
    __shared__ float eh[2][33];
    const int b = blockIdx.x;                      // 4096 pairs
    const int p0 = ((b & 7) * 512 + (b >> 3)) * 2; // XCD-contiguous sorted ranges
    const int half = threadIdx.x >> 7;
    const int o = threadIdx.x & 127;
    if (o < 33) eh[half][o] = ehP[(size_t)(p0 + half) * 33 + o];
    __syncthreads();
    const int2 e = rc[p0 + half];
    const _Float16* Ur = U + (size_t)e.x * ULD;
    float acc = eh[half][32] * (float)Ur[4096 + o];
#pragma unroll
    for (int k = 0; k < 32; ++k) acc += eh[half][k] * (float)Ur[k * 128 + o];
    atomicAdd(&agg[(size_t)e.y * 128 + o], acc);
}

// GRU gate combine; updates xh fp32 + Ax fp16; fused pooling on last step
__global__ void gate_k(const float* __restrict__ G1, const float* __restrict__ G2,
                       float* __restrict__ xh, _Float16* __restrict__ Ax,
                       const int* __restrict__ batch, float* __restrict__ pooled) {
    const int idx = blockIdx.x * 256 + threadIdx.x;
    const int n = idx >> 7, o = idx & 127;
    const size_t b = (size_t)n * 384;
    float ir = G1[b + o], iz = G1[b + 128 + o], in_ = G1[b + 256 + o];
    float hr = G2[b + o], hz = G2[b + 128 + o], hn = G2[b + 256 + o];
    float r = 1.f / (1.f + expf(-(ir + hr)));
    float z = 1.f / (1.f + expf(-(iz + hz)));
    float nv = tanhf(in_ + r * hn);
    float hv = (1.f - z) * nv + z * xh[idx];
    xh[idx] = hv;
    Ax[idx] = (_Float16)hv;
    if (pooled) atomicAdd(&pooled[batch[n] * 128 + o], hv);
}

// Big B'T[t][j(4352)][128] fp16: j<4096 -> W2; <4224 -> b2; else root_w
__global__ void convb_big_k(const float* __restrict__ w2, const float* __restrict__ b2,
                            const float* __restrict__ rw, _Float16* __restrict__ BT) {
    const int t = blockIdx.y;
    const int idx = blockIdx.x * 256 + threadIdx.x;   // 4352*128
    const int j = idx >> 7, h = idx & 127;
    float v;
    if (j < 4096)      v = w2[(size_t)t * 524288 + (size_t)(j >> 7) * 16384 + h * 128 + (j & 127)];
    else if (j < 4224) v = b2[t * 16384 + h * 128 + (j - 4096)];
    else               v = rw[t * 16384 + h * 128 + (j - 4224)];
    BT[(size_t)t * 557056 + (size_t)j * 128 + h] = (_Float16)v;
}

__global__ __launch_bounds__(128) void final_k(
    const float* __restrict__ pooled, const float* __restrict__ cnt,
    const float* __restrict__ l1w, const float* __restrict__ l1b,
    const float* __restrict__ l2w, const float* __restrict__ l2b,
    float* __restrict__ out)
{
    __shared__ float gv[128];
    __shared__ float sy[64];
    const int t = threadIdx.x;
    for (int g = 0; g < GG; ++g) {
        float c = cnt[g]; c = c > 1.f ? c : 1.f;
        gv[t] = pooled[g * 128 + t] / c;
        __syncthreads();
        if (t < 64) {
            float y = l1b[t];
            for (int h = 0; h < 128; ++h) y += gv[h] * l1w[h * 64 + t];
            y = y > 0.f ? y : 0.f;
            sy[t] = y * l2w[t];
        }
        __syncthreads();
        if (t == 0) {
            float s = l2b[0];
            for (int j = 0; j < 64; ++j) s += sy[j];
            out[g] = s;
        }
        __syncthreads();
    }
}

extern "C" void kernel_launch(void* const* d_in, const int* in_sizes, int n_in,
                              void* d_out, int out_size, void* d_ws, size_t ws_size,
                              hipStream_t stream) {
    const float* x      = (const float*)d_in[0];
    const int*   ei     = (const int*)d_in[1];
    const float* eattr  = (const float*)d_in[2];
    const int*   batch  = (const int*)d_in[3];
    const float* lin0_w = (const float*)d_in[4];
    const float* lin0_b = (const float*)d_in[5];
    const float* nn_w1  = (const float*)d_in[6];
    const float* nn_b1  = (const float*)d_in[7];
    const float* nn_w2  = (const float*)d_in[8];
    const float* nn_b2  = (const float*)d_in[9];
    const float* root_w = (const float*)d_in[10];
    const float* conv_b = (const float*)d_in[11];
    const float* gwih   = (const float*)d_in[12];
    const float* gwhh   = (const float*)d_in[13];
    const float* gbih   = (const float*)d_in[14];
    const float* gbhh   = (const float*)d_in[15];
    const float* l1w    = (const float*)d_in[16];
    const float* l1b    = (const float*)d_in[17];
    const float* l2w    = (const float*)d_in[18];
    const float* l2b    = (const float*)d_in[19];
    float* out = (float*)d_out;
    float* ws  = (float*)d_ws;

    // ---- workspace layout (float offsets; zero region first, contiguous) ----
    float*    agg0   = ws;                          // 3 x [4096,128]
    float*    pooled = ws + 1572864;                // [8,128]
    float*    cnt    = ws + 1573888;                // [8]
    float*    deg    = ws + 1573896;                // [4096]
    int*      odeg   = (int*)(ws + 1577992);        // [4096]
    // zero region ends at 1582088 floats = 6328352 bytes
    int*      ocur   = (int*)(ws + 1582088);        // [4096]
    int2*     rc     = (int2*)(ws + 1586184);       // [8192]
    float*    ehP    = ws + 1602568;                // [3,8192,33]
    float*    xh     = ws + 2413576;                // [4096,128]
    float*    g1     = ws + 2937864;                // [4096,384]
    float*    g2     = ws + 4510728;                // [4096,384]
    _Float16* bigC   = (_Float16*)(ws + 6083592);   // [4096,4352] fp16
    _Float16* Ax     = (_Float16*)(ws + 14996488);  // [4096,128] fp16
    _Float16* BTu    = (_Float16*)(ws + 15258632);  // 3 x [4352,128] fp16
    _Float16* Bih16  = (_Float16*)(ws + 16094216);  // [384,128] fp16
    _Float16* Bhh16  = (_Float16*)(ws + 16118792);  // [384,128] fp16

    hipMemsetAsync(agg0, 0, 6328352, stream);
    setup_k<<<240, 256, 0, stream>>>(gwih, gwhh, Bih16, Bhh16, ei, batch, deg, odeg, cnt);
    scan_k<<<1, 256, 0, stream>>>(odeg, ocur);
    scatter_k<<<EE / 256, 256, 0, stream>>>(ei, eattr, nn_w1, nn_b1, deg, ocur, rc, ehP);
    convb_big_k<<<dim3(2176, 3), 256, 0, stream>>>(nn_w2, nn_b2, root_w, BTu);
    lin0_k<<<dim3(2, 64), 256, 0, stream>>>(x, lin0_w, lin0_b, xh, Ax);

    for (int t = 0; t < 3; ++t) {
        float* agg = agg0 + (size_t)t * 524288;
        mgemm16_k<<<dim3(34, 32), 256, 0, stream>>>(Ax, BTu + (size_t)t * 557056, bigC);
        edge_msg_k<<<EE / 2, 256, 0, stream>>>(rc, ehP + (size_t)t * EE * 33, bigC, agg);
        gru_k<<<dim3(3, 32, 2), 256, 0, stream>>>(bigC, agg, conv_b + t * 128, Ax,
                                                  Bih16, Bhh16, gbih, gbhh, g1, g2);
        gate_k<<<2048, 256, 0, stream>>>(g1, g2, xh, Ax, batch,
                                         (t == 2) ? pooled : nullptr);
    }

    final_k<<<1, 128, 0, stream>>>(pooled, cnt, l1w, l1b, l2w, l2b, out);
}